// Round 2
// baseline (8230.811 us; speedup 1.0000x reference)
//
#include <hip/hip_runtime.h>
#include <hip/hip_bf16.h>

using f32x4  = __attribute__((ext_vector_type(4))) float;
using bf16x8 = __attribute__((ext_vector_type(8))) __bf16;
using u64    = unsigned long long;

#define T_DIM 512
#define B_DIM 64
#define D_DIM 1024
#define H_DIM 1024
#define G_DIM 4096   // 4*H
#define NWG   64     // workgroups in the scan kernel (fewer, fatter: 4x less h broadcast)
#define WGT   1024   // threads per scan workgroup (16 waves)

// ---------------------------------------------------------------------------
// fp32 -> bf16 conversion (vectorized 8/thread)
// ---------------------------------------------------------------------------
__global__ void f32_to_bf16_kernel(const float* __restrict__ src,
                                   __bf16* __restrict__ dst, long n) {
    long i = ((long)blockIdx.x * blockDim.x + threadIdx.x) * 8;
    if (i + 8 <= n) {
        f32x4 a = *(const f32x4*)(src + i);
        f32x4 b = *(const f32x4*)(src + i + 4);
        bf16x8 o;
        o[0] = (__bf16)a[0]; o[1] = (__bf16)a[1];
        o[2] = (__bf16)a[2]; o[3] = (__bf16)a[3];
        o[4] = (__bf16)b[0]; o[5] = (__bf16)b[1];
        o[6] = (__bf16)b[2]; o[7] = (__bf16)b[3];
        *(bf16x8*)(dst + i) = o;
    }
}

// ---------------------------------------------------------------------------
// Phase 1: xg[M][4096] = A[M][1024](bf16) @ W[4096][1024]^T (bf16) + bias
// (unchanged — scan kernel is 78% of runtime)
// ---------------------------------------------------------------------------
#define BM 128
#define BN 128
#define BK 64

__global__ __launch_bounds__(256) void gemm_xg_kernel(
    const __bf16* __restrict__ A,    // [M][1024]
    const __bf16* __restrict__ W,    // [4096][1024]
    const float* __restrict__ bias,  // [4096]
    float* __restrict__ C,           // [M][4096]
    int M)
{
    (void)M;
    __shared__ __bf16 sA[BM * BK];
    __shared__ __bf16 sB[BN * BK];

    const int tid = threadIdx.x;
    const int wv  = tid >> 6;
    const int l   = tid & 63;
    const int wy  = wv >> 1, wx = wv & 1;
    const int bm  = blockIdx.y * BM;
    const int bn  = blockIdx.x * BN;
    const int n   = l & 15;
    const int q   = l >> 4;

    const int srow  = l >> 3;
    const int skoff = (l & 7) * 8;

    f32x4 acc[4][4];
    #pragma unroll
    for (int mt = 0; mt < 4; ++mt)
        #pragma unroll
        for (int nt = 0; nt < 4; ++nt)
            acc[mt][nt] = (f32x4){0.f, 0.f, 0.f, 0.f};

    for (int kt = 0; kt < D_DIM / BK; ++kt) {
        const int k0 = kt * BK;
        #pragma unroll
        for (int j = 0; j < 4; ++j) {
            const int rbase = (j * 4 + wv) * 8;
            const __bf16* ga = A + (long)(bm + rbase + srow) * D_DIM + k0 + skoff;
            const __bf16* gb = W + (long)(bn + rbase + srow) * D_DIM + k0 + skoff;
            __builtin_amdgcn_global_load_lds(
                (const __attribute__((address_space(1))) void*)ga,
                (__attribute__((address_space(3))) void*)(sA + rbase * BK), 16, 0, 0);
            __builtin_amdgcn_global_load_lds(
                (const __attribute__((address_space(1))) void*)gb,
                (__attribute__((address_space(3))) void*)(sB + rbase * BK), 16, 0, 0);
        }
        __syncthreads();

        #pragma unroll
        for (int ks = 0; ks < 2; ++ks) {
            bf16x8 af[4], bfr[4];
            #pragma unroll
            for (int mt = 0; mt < 4; ++mt) {
                int row = wy * 64 + mt * 16 + n;
                af[mt] = *(const bf16x8*)(sA + row * BK + ks * 32 + q * 8);
            }
            #pragma unroll
            for (int nt = 0; nt < 4; ++nt) {
                int col = wx * 64 + nt * 16 + n;
                bfr[nt] = *(const bf16x8*)(sB + col * BK + ks * 32 + q * 8);
            }
            #pragma unroll
            for (int mt = 0; mt < 4; ++mt)
                #pragma unroll
                for (int nt = 0; nt < 4; ++nt)
                    acc[mt][nt] = __builtin_amdgcn_mfma_f32_16x16x32_bf16(
                        af[mt], bfr[nt], acc[mt][nt], 0, 0, 0);
        }
        __syncthreads();
    }

    #pragma unroll
    for (int nt = 0; nt < 4; ++nt) {
        int col = bn + wx * 64 + nt * 16 + n;
        float b = bias[col];
        #pragma unroll
        for (int mt = 0; mt < 4; ++mt) {
            #pragma unroll
            for (int r = 0; r < 4; ++r) {
                int row = bm + wy * 64 + mt * 16 + q * 4 + r;
                C[(long)row * G_DIM + col] = acc[mt][nt][r] + b;
            }
        }
    }
}

// ---------------------------------------------------------------------------
// fast tanh via __expf. x->+inf: 1; x->-inf: -1. err ~1e-6, tol 1.5e-2.
// ---------------------------------------------------------------------------
__device__ __forceinline__ float fast_tanh(float x) {
    return 1.0f - 2.0f / (__expf(2.0f * x) + 1.0f);
}

// ---------------------------------------------------------------------------
// Fence-free grid barrier over NWG=64 workgroups.
// h stores are agent-scope relaxed atomics (write-through to MALL). The
// __syncthreads() before the flag publish makes the compiler emit
// s_waitcnt vmcnt(0) in every wave, so all h stores are globally visible
// before tid 0 publishes. Poll: wave 0, one flag per lane, s_sleep backoff.
// No inline asm anywhere (round-1 lesson: untracked VMEM + deferred waits
// breaks under register pressure).
// ---------------------------------------------------------------------------
__device__ __forceinline__ void grid_barrier(unsigned* __restrict__ flags,
                                             unsigned target, int tid, int wgid) {
    __syncthreads();   // all waves: vmcnt(0) -> h stores visible at MALL
    if (tid == 0)
        __hip_atomic_store(&flags[wgid], target, __ATOMIC_RELAXED,
                           __HIP_MEMORY_SCOPE_AGENT);
    if (tid < 64) {
        for (;;) {
            unsigned v = __hip_atomic_load(&flags[tid], __ATOMIC_RELAXED,
                                           __HIP_MEMORY_SCOPE_AGENT);
            if (__all(v >= target)) break;
            __builtin_amdgcn_s_sleep(1);
        }
    }
    __syncthreads();
    __atomic_signal_fence(__ATOMIC_ACQUIRE);   // compiler-only: keep h loads after poll
}

// ---------------------------------------------------------------------------
// Phase 2: persistent scan. 64 wgs x 1024 thr (16 waves); wg owns 16 hidden
// units. Wave wv = (sub, wq): sub = wv>>2 picks a 4-unit subgroup, wq = wv&3
// picks a 16-row batch quarter. The 4 waves sharing a row quarter read h from
// LDS instead of each re-reading MALL: per-wg h traffic stays 128 KB but
// NWG drops 256 -> 64, cutting the coherent h broadcast 32 MB -> 8 MB/step.
//
// h is staged per K-quarter (256 units = 32 KB) into XOR-swizzled LDS:
//   - loads: compiler-tracked u64 agent atomics; each wave-instruction loads
//     one contiguous 512 B row-quarter (8x64B requests, every byte used)
//   - T14: quarter kq+1's loads issue right after kq's ds_writes, hiding
//     MALL latency under kq's MFMA + barriers
//   - swizzle: byte ^= ((row&7)<<4) -> 2-way conflicts on ds_read_b128 (free)
// ---------------------------------------------------------------------------
__global__ __launch_bounds__(WGT, 1) void lstm_scan_kernel(
    const __bf16* __restrict__ Whb,   // [4096][1024] bf16
    const float* __restrict__ xg,     // [tc][64][4096] fp32 (chunk-local)
    const float* __restrict__ mask,   // [512][64]
    float* __restrict__ cst,          // [64][1024] fp32 chunk-boundary state
    __bf16* __restrict__ hbuf,        // [2][64][1024] bf16 state
    float* __restrict__ out,          // [512][64][1024]
    unsigned* __restrict__ flags,     // [64] barrier flags
    int t0, int tc)
{
    __shared__ f32x4 shq[2048];           // 32 KB: staged h quarter [64 rows][512 B], swizzled
    __shared__ float sg[16][16 * 17];     // per-wave gate exchange (17 KB)
    char* sh = (char*)shq;

    const int tid  = threadIdx.x;
    const int wgid = blockIdx.x;
    const int u0   = wgid * 16;
    const int wv   = tid >> 6;
    const int l    = tid & 63;
    const int n    = l & 15;
    const int q    = l >> 4;
    const int sub  = wv >> 2;             // unit subgroup 0..3
    const int wq   = wv & 3;              // batch-row quarter 0..3
    const int colg = ((n >> 2) << 10) + u0 + (sub << 2) + (n & 3);

    // Wh fragments for this wave's 16 gate columns (compiler may sink to L2 loads)
    bf16x8 breg[32];
    {
        const __bf16* wrow = Whb + (long)colg * H_DIM + q * 8;
        #pragma unroll
        for (int ks = 0; ks < 32; ++ks)
            breg[ks] = *(const bf16x8*)(wrow + ks * 32);
    }

    const int rloc = l >> 2;
    const int ui   = l & 3;
    const int rb   = wq * 16 + rloc;          // batch row owned by this lane
    const int uu   = u0 + (sub << 2) + ui;    // hidden unit owned by this lane

    const int s_w = (wv & 7) << 4;   // stage-write swizzle (row & 7 == wv & 7)
    const int s_r = (n & 7) << 4;    // mfma-read swizzle  (row & 7 == n & 7)
    const int r16 = (wq * 16 + n) * 512;      // mfma-read row base (bytes)

    float c_r, h_r;
    if (t0 == 0) { c_r = 0.0f; h_r = 0.0f; }
    else {
        c_r = cst[rb * H_DIM + uu];
        h_r = out[((long)(t0 - 1) * B_DIM + rb) * H_DIM + uu];
    }

    for (int t = 0; t < tc; ++t) {
        const int gt = t0 + t;
        const __bf16* hread = hbuf + (long)(gt & 1) * (B_DIM * H_DIM);
        __bf16* hwrite = hbuf + (long)((gt + 1) & 1) * (B_DIM * H_DIM);
        u64* hr64 = (u64*)hread;

        // xg/mask loads issue here, consumed after the K loop (latency hidden)
        const float* xgrow = xg + ((long)t * B_DIM + rb) * G_DIM;
        float xgv0 = xgrow[uu];
        float xgv1 = xgrow[H_DIM + uu];
        float xgv2 = xgrow[2 * H_DIM + uu];
        float xgv3 = xgrow[3 * H_DIM + uu];
        float mk   = mask[gt * B_DIM + rb];

        f32x4 ac0 = {0.f, 0.f, 0.f, 0.f};
        f32x4 ac1 = {0.f, 0.f, 0.f, 0.f};

        // preload quarter 0 (4 u64 = one contiguous 512B row-quarter per wave-instr)
        u64 hold[4];
        #pragma unroll
        for (int j = 0; j < 4; ++j)
            hold[j] = __hip_atomic_load(hr64 + (j * 16 + wv) * 256 + l,
                                        __ATOMIC_RELAXED, __HIP_MEMORY_SCOPE_AGENT);

        #pragma unroll
        for (int kq = 0; kq < 4; ++kq) {
            __syncthreads();   // prior quarter's LDS reads complete
            #pragma unroll
            for (int j = 0; j < 4; ++j)
                *(u64*)(sh + (j * 16 + wv) * 512 + ((l * 8) ^ s_w)) = hold[j];
            if (kq < 3) {      // T14: issue next quarter's loads before compute
                #pragma unroll
                for (int j = 0; j < 4; ++j)
                    hold[j] = __hip_atomic_load(
                        hr64 + (j * 16 + wv) * 256 + (kq + 1) * 64 + l,
                        __ATOMIC_RELAXED, __HIP_MEMORY_SCOPE_AGENT);
            }
            __syncthreads();   // staged quarter visible
            #pragma unroll
            for (int kss = 0; kss < 8; kss += 2) {
                bf16x8 a0 = *(const bf16x8*)(sh + r16 + ((kss * 64 + q * 16) ^ s_r));
                bf16x8 a1 = *(const bf16x8*)(sh + r16 + (((kss + 1) * 64 + q * 16) ^ s_r));
                ac0 = __builtin_amdgcn_mfma_f32_16x16x32_bf16(a0, breg[kq * 8 + kss],     ac0, 0, 0, 0);
                ac1 = __builtin_amdgcn_mfma_f32_16x16x32_bf16(a1, breg[kq * 8 + kss + 1], ac1, 0, 0, 0);
            }
        }
        f32x4 acc = ac0 + ac1;

        // gate exchange via per-wave LDS (same-wave write->read, lockstep-safe)
        #pragma unroll
        for (int r = 0; r < 4; ++r)
            sg[wv][(q * 4 + r) * 17 + n] = acc[r];

        float ig = xgv0 + sg[wv][rloc * 17 + 0  + ui];
        float fg = xgv1 + sg[wv][rloc * 17 + 4  + ui];
        float og = xgv2 + sg[wv][rloc * 17 + 8  + ui];
        float gg = xgv3 + sg[wv][rloc * 17 + 12 + ui];

        float i_s = 1.0f / (1.0f + __expf(-ig));
        float f_s = 1.0f / (1.0f + __expf(-fg));
        float o_s = 1.0f / (1.0f + __expf(-og));
        float g_t = fast_tanh(gg);
        float c_new = f_s * c_r + i_s * g_t;
        float h_new = o_s * fast_tanh(c_new);
        float c_f = mk * c_new + (1.0f - mk) * c_r;
        float h_f = mk * h_new + (1.0f - mk) * h_r;
        c_r = c_f;
        h_r = h_f;

        // write-through h store (round-0-proven path)
        unsigned short hsb = __builtin_bit_cast(unsigned short, (__bf16)h_f);
        __hip_atomic_store((unsigned short*)hwrite + (long)rb * H_DIM + uu, hsb,
                           __ATOMIC_RELAXED, __HIP_MEMORY_SCOPE_AGENT);
        out[((long)gt * B_DIM + rb) * H_DIM + uu] = h_f;
        if (t == tc - 1) cst[rb * H_DIM + uu] = c_f;

        grid_barrier(flags, (unsigned)(gt + 1), tid, wgid);
    }
}

// ---------------------------------------------------------------------------
// Host side. Workspace:
//   [Whb 8MiB][Wxb 8MiB][hbuf 2x128KiB][cst 256KiB][flags 1KiB] (pad to 1MiB)
//   [xb chunk][xg chunk]
// ---------------------------------------------------------------------------
extern "C" void kernel_launch(void* const* d_in, const int* in_sizes, int n_in,
                              void* d_out, int out_size, void* d_ws, size_t ws_size,
                              hipStream_t stream)
{
    (void)in_sizes; (void)n_in; (void)out_size;
    const float* x     = (const float*)d_in[0];  // [512][64][1024]
    const float* xmask = (const float*)d_in[1];  // [512][64]
    const float* Wx    = (const float*)d_in[2];  // [4096][1024]
    const float* bx    = (const float*)d_in[3];  // [4096]
    const float* Wh    = (const float*)d_in[4];  // [4096][1024]
    float* out = (float*)d_out;

    char* ws = (char*)d_ws;
    __bf16*   Whb   = (__bf16*)(ws);
    __bf16*   Wxb   = (__bf16*)(ws + 8388608);
    __bf16*   hb    = (__bf16*)(ws + 16777216);             // 2 x 131072 B
    float*    cst   = (float*)(ws + 16777216 + 262144);     // 262144 B
    unsigned* flags = (unsigned*)(ws + 16777216 + 524288);  // 1024 B
    char* dyn = ws + 16777216 + 1048576;

    long avail = (long)ws_size - (16777216L + 1048576L);
    const long per_t = (long)B_DIM * D_DIM * 2 + (long)B_DIM * G_DIM * 4;
    long Tc = avail > 0 ? avail / per_t : 2;
    if (Tc > T_DIM) Tc = T_DIM;
    Tc &= ~1L;
    if (Tc < 2) Tc = 2;

    __bf16* xb = (__bf16*)dyn;
    float*  xg = (float*)(dyn + Tc * (long)B_DIM * D_DIM * 2);

    // zero h0 state + barrier flags
    hipMemsetAsync(ws + 16777216, 0, 1048576, stream);

    {
        long nw = (long)G_DIM * D_DIM;
        int nb = (int)(nw / 8 / 256);
        f32_to_bf16_kernel<<<nb, 256, 0, stream>>>(Wx, Wxb, nw);
        f32_to_bf16_kernel<<<nb, 256, 0, stream>>>(Wh, Whb, nw);
    }

    for (int t0 = 0; t0 < T_DIM; t0 += (int)Tc) {
        int tc = (int)((T_DIM - t0 < Tc) ? (long)(T_DIM - t0) : Tc);

        long nx = (long)tc * B_DIM * D_DIM;
        f32_to_bf16_kernel<<<(int)(nx / 8 / 256), 256, 0, stream>>>(
            x + (long)t0 * B_DIM * D_DIM, xb, nx);

        dim3 gg(G_DIM / BN, (tc * B_DIM) / BM);
        gemm_xg_kernel<<<gg, 256, 0, stream>>>(xb, Wxb, bx, xg, tc * B_DIM);

        const __bf16* Whb_a = Whb;
        const float*  xg_a  = xg;
        const float*  mask_a = xmask;
        float*  cst_a = cst;
        __bf16* hb_a  = hb;
        float*  out_a = out;
        unsigned* fl_a = flags;
        int t0_a = t0, tc_a = tc;
        void* args[] = {(void*)&Whb_a, (void*)&xg_a, (void*)&mask_a,
                        (void*)&cst_a, (void*)&hb_a, (void*)&out_a,
                        (void*)&fl_a, (void*)&t0_a, (void*)&tc_a};
        hipLaunchCooperativeKernel((void*)lstm_scan_kernel, dim3(NWG), dim3(WGT),
                                   args, 0, stream);
    }
}

// Round 3
// 5126.166 us; speedup vs baseline: 1.6056x; 1.6056x over previous
//
#include <hip/hip_runtime.h>
#include <hip/hip_bf16.h>

using f32x4  = __attribute__((ext_vector_type(4))) float;
using bf16x8 = __attribute__((ext_vector_type(8))) __bf16;
using u64    = unsigned long long;

#define T_DIM 512
#define B_DIM 64
#define D_DIM 1024
#define H_DIM 1024
#define G_DIM 4096   // 4*H
#define NWG   128    // scan workgroups (wg owns 8 hidden units)
#define WGT   512    // threads per scan wg (8 waves)

// ---------------------------------------------------------------------------
// fp32 -> bf16 conversion (vectorized 8/thread)
// ---------------------------------------------------------------------------
__global__ void f32_to_bf16_kernel(const float* __restrict__ src,
                                   __bf16* __restrict__ dst, long n) {
    long i = ((long)blockIdx.x * blockDim.x + threadIdx.x) * 8;
    if (i + 8 <= n) {
        f32x4 a = *(const f32x4*)(src + i);
        f32x4 b = *(const f32x4*)(src + i + 4);
        bf16x8 o;
        o[0] = (__bf16)a[0]; o[1] = (__bf16)a[1];
        o[2] = (__bf16)a[2]; o[3] = (__bf16)a[3];
        o[4] = (__bf16)b[0]; o[5] = (__bf16)b[1];
        o[6] = (__bf16)b[2]; o[7] = (__bf16)b[3];
        *(bf16x8*)(dst + i) = o;
    }
}

// ---------------------------------------------------------------------------
// Phase 1: xg[M][4096] = A[M][1024](bf16) @ W[4096][1024]^T (bf16) + bias
// (unchanged — scan kernel is ~78% of runtime)
// ---------------------------------------------------------------------------
#define BM 128
#define BN 128
#define BK 64

__global__ __launch_bounds__(256) void gemm_xg_kernel(
    const __bf16* __restrict__ A,    // [M][1024]
    const __bf16* __restrict__ W,    // [4096][1024]
    const float* __restrict__ bias,  // [4096]
    float* __restrict__ C,           // [M][4096]
    int M)
{
    (void)M;
    __shared__ __bf16 sA[BM * BK];
    __shared__ __bf16 sB[BN * BK];

    const int tid = threadIdx.x;
    const int wv  = tid >> 6;
    const int l   = tid & 63;
    const int wy  = wv >> 1, wx = wv & 1;
    const int bm  = blockIdx.y * BM;
    const int bn  = blockIdx.x * BN;
    const int n   = l & 15;
    const int q   = l >> 4;

    const int srow  = l >> 3;
    const int skoff = (l & 7) * 8;

    f32x4 acc[4][4];
    #pragma unroll
    for (int mt = 0; mt < 4; ++mt)
        #pragma unroll
        for (int nt = 0; nt < 4; ++nt)
            acc[mt][nt] = (f32x4){0.f, 0.f, 0.f, 0.f};

    for (int kt = 0; kt < D_DIM / BK; ++kt) {
        const int k0 = kt * BK;
        #pragma unroll
        for (int j = 0; j < 4; ++j) {
            const int rbase = (j * 4 + wv) * 8;
            const __bf16* ga = A + (long)(bm + rbase + srow) * D_DIM + k0 + skoff;
            const __bf16* gb = W + (long)(bn + rbase + srow) * D_DIM + k0 + skoff;
            __builtin_amdgcn_global_load_lds(
                (const __attribute__((address_space(1))) void*)ga,
                (__attribute__((address_space(3))) void*)(sA + rbase * BK), 16, 0, 0);
            __builtin_amdgcn_global_load_lds(
                (const __attribute__((address_space(1))) void*)gb,
                (__attribute__((address_space(3))) void*)(sB + rbase * BK), 16, 0, 0);
        }
        __syncthreads();

        #pragma unroll
        for (int ks = 0; ks < 2; ++ks) {
            bf16x8 af[4], bfr[4];
            #pragma unroll
            for (int mt = 0; mt < 4; ++mt) {
                int row = wy * 64 + mt * 16 + n;
                af[mt] = *(const bf16x8*)(sA + row * BK + ks * 32 + q * 8);
            }
            #pragma unroll
            for (int nt = 0; nt < 4; ++nt) {
                int col = wx * 64 + nt * 16 + n;
                bfr[nt] = *(const bf16x8*)(sB + col * BK + ks * 32 + q * 8);
            }
            #pragma unroll
            for (int mt = 0; mt < 4; ++mt)
                #pragma unroll
                for (int nt = 0; nt < 4; ++nt)
                    acc[mt][nt] = __builtin_amdgcn_mfma_f32_16x16x32_bf16(
                        af[mt], bfr[nt], acc[mt][nt], 0, 0, 0);
        }
        __syncthreads();
    }

    #pragma unroll
    for (int nt = 0; nt < 4; ++nt) {
        int col = bn + wx * 64 + nt * 16 + n;
        float b = bias[col];
        #pragma unroll
        for (int mt = 0; mt < 4; ++mt) {
            #pragma unroll
            for (int r = 0; r < 4; ++r) {
                int row = bm + wy * 64 + mt * 16 + q * 4 + r;
                C[(long)row * G_DIM + col] = acc[mt][nt][r] + b;
            }
        }
    }
}

// ---------------------------------------------------------------------------
// fast tanh via __expf. err ~1e-6, tol 1.5e-2.
// ---------------------------------------------------------------------------
__device__ __forceinline__ float fast_tanh(float x) {
    return 1.0f - 2.0f / (__expf(2.0f * x) + 1.0f);
}

// ---------------------------------------------------------------------------
// Grid barrier: single MALL atomic counter. h stores (agent-scope atomics,
// write-through) are drained by each wave's vmcnt(0) at __syncthreads before
// tid 0 adds, so counter >= target implies all h(t+1) visible. One wave polls
// one broadcast line (64 same-address lanes = 1 request) with short backoff.
// ---------------------------------------------------------------------------
__device__ __forceinline__ void grid_barrier(unsigned* __restrict__ cnt,
                                             unsigned target, int tid) {
    __syncthreads();   // all waves: vmcnt(0) -> h stores visible at MALL
    if (tid == 0)
        __hip_atomic_fetch_add(cnt, 1u, __ATOMIC_RELAXED, __HIP_MEMORY_SCOPE_AGENT);
    if (tid < 64) {
        while (__hip_atomic_load(cnt, __ATOMIC_RELAXED,
                                 __HIP_MEMORY_SCOPE_AGENT) < target)
            __builtin_amdgcn_s_sleep(2);
    }
    __syncthreads();
    __atomic_signal_fence(__ATOMIC_ACQUIRE);   // compiler-only: keep h loads after poll
}

// ---------------------------------------------------------------------------
// Phase 2: persistent scan. 128 wgs x 512 thr (8 waves); wg owns 8 hidden
// units (32 gate cols). Wave wv = (ksl = wv>>1: K-slice 0..3, sub = wv&1:
// 4-unit subgroup). Each wave computes a 64-row x 16-col PARTIAL gate tile
// over K=256 -> breg is only 8 bf16x8 = 32 VGPRs (total demand ~140 << 256
// cap) so Wh provably stays register-resident across the t-loop (round-2
// post-mortem: VGPR_Count=64 proved the compiler was re-loading Wh from L2
// every step). Partials are reduced across ksl through padded LDS.
// h staged in two 64KB halves; BOTH halves' loads issue in one burst right
// after barrier detect (single MALL RT on the critical path).
// ---------------------------------------------------------------------------
__global__ __launch_bounds__(WGT, 1) void lstm_scan_kernel(
    const __bf16* __restrict__ Whb,   // [4096][1024] bf16
    const float* __restrict__ xg,     // [tc][64][4096] fp32 (chunk-local)
    const float* __restrict__ mask,   // [512][64]
    float* __restrict__ cst,          // [64][1024] fp32 chunk-boundary state
    __bf16* __restrict__ hbuf,        // [2][64][1024] bf16 state
    float* __restrict__ out,          // [512][64][1024]
    unsigned* __restrict__ flags,     // counter at flags[0]
    int t0, int tc)
{
    __shared__ __align__(16) char shh[65536];   // staged h half: [64 rows][1024B], swizzled
    __shared__ float red[4][64][36];            // partial gates [ksl][row][32 cols + pad]
    __shared__ float hp[8][64];                 // per-wave h pack

    const int tid  = threadIdx.x;
    const int wgid = blockIdx.x;
    const int wv   = tid >> 6;
    const int l    = tid & 63;
    const int n    = l & 15;
    const int q    = l >> 4;
    const int ksl  = wv >> 1;        // K-slice 0..3 (K range: ksl*... interleaved by half)
    const int sub  = wv & 1;         // unit subgroup 0..1
    const int wv8  = wv * 8;

    // B columns: global gate col = (n>>2)*H + wgid*8 + sub*4 + (n&3)
    const int colg = ((n >> 2) << 10) + wgid * 8 + (sub << 2) + (n & 3);

    // Wh fragments: 8 per wave (32 VGPRs) — k = hh*512 + ksl*128 + j*32 + q*8
    bf16x8 breg[8];
    #pragma unroll
    for (int hh = 0; hh < 2; ++hh)
        #pragma unroll
        for (int j = 0; j < 4; ++j)
            breg[hh * 4 + j] = *(const bf16x8*)(
                Whb + (long)colg * H_DIM + hh * 512 + ksl * 128 + j * 32 + q * 8);

    // gate-phase ownership: one (row, unit) per thread
    const int grow = tid >> 3;       // batch row 0..63
    const int gu   = tid & 7;        // unit-in-wg 0..7
    const int gsub = gu >> 2, guo = gu & 3;
    const int ucol = wgid * 8 + gu;  // global hidden unit

    float c_r, h_r;
    if (t0 == 0) { c_r = 0.0f; h_r = 0.0f; }
    else {
        c_r = cst[grow * H_DIM + ucol];
        h_r = out[((long)(t0 - 1) * B_DIM + grow) * H_DIM + ucol];
    }

    // prefetch xg/mask for t = 0
    float xc0, xc1, xc2, xc3, mkc;
    {
        const float* xr = xg + (long)grow * G_DIM + ucol;
        xc0 = xr[0]; xc1 = xr[H_DIM]; xc2 = xr[2 * H_DIM]; xc3 = xr[3 * H_DIM];
        mkc = mask[t0 * B_DIM + grow];
    }

    for (int t = 0; t < tc; ++t) {
        const int gt = t0 + t;
        const __bf16* hread = hbuf + (long)(gt & 1) * (B_DIM * H_DIM);
        __bf16* hwrite = hbuf + (long)((gt + 1) & 1) * (B_DIM * H_DIM);
        const u64* h64 = (const u64*)hread;

        // issue ALL h loads (both halves) in one burst: per instr one wave reads
        // a contiguous 512B row-slice (fully coalesced, MALL-coherent)
        u64 hold0[16], hold1[16];
        #pragma unroll
        for (int j = 0; j < 8; ++j) {
            const long rbase = (long)(wv8 + j) * 256;   // u64 index of row start
            hold0[j * 2]     = __hip_atomic_load(h64 + rbase + l,       __ATOMIC_RELAXED, __HIP_MEMORY_SCOPE_AGENT);
            hold0[j * 2 + 1] = __hip_atomic_load(h64 + rbase + 64 + l,  __ATOMIC_RELAXED, __HIP_MEMORY_SCOPE_AGENT);
            hold1[j * 2]     = __hip_atomic_load(h64 + rbase + 128 + l, __ATOMIC_RELAXED, __HIP_MEMORY_SCOPE_AGENT);
            hold1[j * 2 + 1] = __hip_atomic_load(h64 + rbase + 192 + l, __ATOMIC_RELAXED, __HIP_MEMORY_SCOPE_AGENT);
        }

        f32x4 acc[4];
        #pragma unroll
        for (int m = 0; m < 4; ++m) acc[m] = (f32x4){0.f, 0.f, 0.f, 0.f};

        // stage half 0 (rows wv8..wv8+7, bytes [0,1024) of each row's 2KB)
        #pragma unroll
        for (int j = 0; j < 8; ++j) {
            char* base = shh + (wv8 + j) * 1024;
            const int swz = (j & 7) << 4;               // (wv8+j)&7 == j&7
            *(u64*)(base + ((l * 8) ^ swz))       = hold0[j * 2];
            *(u64*)(base + ((l * 8 + 512) ^ swz)) = hold0[j * 2 + 1];
        }
        __syncthreads();

        // phase 0 MFMA: k in [ksl*... within half 0]
        #pragma unroll
        for (int j = 0; j < 4; ++j) {
            #pragma unroll
            for (int m = 0; m < 4; ++m) {
                const int arow = m * 16 + n;
                const bf16x8 af = *(const bf16x8*)(shh + arow * 1024 +
                    ((ksl * 256 + j * 64 + q * 16) ^ ((n & 7) << 4)));
                acc[m] = __builtin_amdgcn_mfma_f32_16x16x32_bf16(af, breg[j], acc[m], 0, 0, 0);
            }
        }
        __syncthreads();   // buffer free

        // stage half 1
        #pragma unroll
        for (int j = 0; j < 8; ++j) {
            char* base = shh + (wv8 + j) * 1024;
            const int swz = (j & 7) << 4;
            *(u64*)(base + ((l * 8) ^ swz))       = hold1[j * 2];
            *(u64*)(base + ((l * 8 + 512) ^ swz)) = hold1[j * 2 + 1];
        }
        __syncthreads();

        // phase 1 MFMA
        #pragma unroll
        for (int j = 0; j < 4; ++j) {
            #pragma unroll
            for (int m = 0; m < 4; ++m) {
                const int arow = m * 16 + n;
                const bf16x8 af = *(const bf16x8*)(shh + arow * 1024 +
                    ((ksl * 256 + j * 64 + q * 16) ^ ((n & 7) << 4)));
                acc[m] = __builtin_amdgcn_mfma_f32_16x16x32_bf16(af, breg[4 + j], acc[m], 0, 0, 0);
            }
        }

        // write K-slice partials (C/D layout: row = q*4+r, col = n)
        #pragma unroll
        for (int m = 0; m < 4; ++m)
            #pragma unroll
            for (int r = 0; r < 4; ++r)
                red[ksl][m * 16 + q * 4 + r][sub * 16 + n] = acc[m][r];
        __syncthreads();

        // gate math: reduce 4 K-slices, one (row, unit) per thread
        float s0 = 0.f, s1 = 0.f, s2 = 0.f, s3 = 0.f;
        #pragma unroll
        for (int ks = 0; ks < 4; ++ks) {
            s0 += red[ks][grow][gsub * 16 + 0  + guo];
            s1 += red[ks][grow][gsub * 16 + 4  + guo];
            s2 += red[ks][grow][gsub * 16 + 8  + guo];
            s3 += red[ks][grow][gsub * 16 + 12 + guo];
        }
        float ig = xc0 + s0, fg = xc1 + s1, og = xc2 + s2, gg = xc3 + s3;
        float i_s = 1.0f / (1.0f + __expf(-ig));
        float f_s = 1.0f / (1.0f + __expf(-fg));
        float o_s = 1.0f / (1.0f + __expf(-og));
        float g_t = fast_tanh(gg);
        float c_new = f_s * c_r + i_s * g_t;
        float h_new = o_s * fast_tanh(c_new);
        float c_f = mkc * c_new + (1.0f - mkc) * c_r;
        float h_f = mkc * h_new + (1.0f - mkc) * h_r;
        c_r = c_f;
        h_r = h_f;

        // pack h per-wave in LDS (same-wave write->read), store as 8B atomics
        hp[wv][l] = h_f;
        if (l < 16) {
            const int rr = l >> 1, part = l & 1;
            float v0 = hp[wv][rr * 8 + part * 4 + 0];
            float v1 = hp[wv][rr * 8 + part * 4 + 1];
            float v2 = hp[wv][rr * 8 + part * 4 + 2];
            float v3 = hp[wv][rr * 8 + part * 4 + 3];
            unsigned short b0 = __builtin_bit_cast(unsigned short, (__bf16)v0);
            unsigned short b1 = __builtin_bit_cast(unsigned short, (__bf16)v1);
            unsigned short b2 = __builtin_bit_cast(unsigned short, (__bf16)v2);
            unsigned short b3 = __builtin_bit_cast(unsigned short, (__bf16)v3);
            u64 pk = (u64)b0 | ((u64)b1 << 16) | ((u64)b2 << 32) | ((u64)b3 << 48);
            u64* dp = (u64*)((unsigned short*)hwrite +
                             (long)(wv8 + rr) * H_DIM + wgid * 8 + part * 4);
            __hip_atomic_store(dp, pk, __ATOMIC_RELAXED, __HIP_MEMORY_SCOPE_AGENT);
        }

        out[((long)gt * B_DIM + grow) * H_DIM + ucol] = h_f;
        if (t == tc - 1) cst[grow * H_DIM + ucol] = c_f;

        // prefetch next step's xg/mask (off the post-barrier critical path)
        if (t + 1 < tc) {
            const float* xr = xg + ((long)(t + 1) * B_DIM + grow) * G_DIM + ucol;
            xc0 = xr[0]; xc1 = xr[H_DIM]; xc2 = xr[2 * H_DIM]; xc3 = xr[3 * H_DIM];
            mkc = mask[(gt + 1) * B_DIM + grow];
        }

        grid_barrier(flags, (unsigned)(gt + 1) * NWG, tid);
    }
}

// ---------------------------------------------------------------------------
// Host side. Workspace:
//   [Whb 8MiB][Wxb 8MiB][hbuf 2x128KiB][cst 256KiB][flags 1KiB] (pad to 1MiB)
//   [xb chunk][xg chunk]
// ---------------------------------------------------------------------------
extern "C" void kernel_launch(void* const* d_in, const int* in_sizes, int n_in,
                              void* d_out, int out_size, void* d_ws, size_t ws_size,
                              hipStream_t stream)
{
    (void)in_sizes; (void)n_in; (void)out_size;
    const float* x     = (const float*)d_in[0];  // [512][64][1024]
    const float* xmask = (const float*)d_in[1];  // [512][64]
    const float* Wx    = (const float*)d_in[2];  // [4096][1024]
    const float* bx    = (const float*)d_in[3];  // [4096]
    const float* Wh    = (const float*)d_in[4];  // [4096][1024]
    float* out = (float*)d_out;

    char* ws = (char*)d_ws;
    __bf16*   Whb   = (__bf16*)(ws);
    __bf16*   Wxb   = (__bf16*)(ws + 8388608);
    __bf16*   hb    = (__bf16*)(ws + 16777216);             // 2 x 131072 B
    float*    cst   = (float*)(ws + 16777216 + 262144);     // 262144 B
    unsigned* flags = (unsigned*)(ws + 16777216 + 524288);  // counter
    char* dyn = ws + 16777216 + 1048576;

    long avail = (long)ws_size - (16777216L + 1048576L);
    const long per_t = (long)B_DIM * D_DIM * 2 + (long)B_DIM * G_DIM * 4;
    long Tc = avail > 0 ? avail / per_t : 2;
    if (Tc > T_DIM) Tc = T_DIM;
    Tc &= ~1L;
    if (Tc < 2) Tc = 2;

    __bf16* xb = (__bf16*)dyn;
    float*  xg = (float*)(dyn + Tc * (long)B_DIM * D_DIM * 2);

    // zero h0 state + barrier counter
    hipMemsetAsync(ws + 16777216, 0, 1048576, stream);

    {
        long nw = (long)G_DIM * D_DIM;
        int nb = (int)(nw / 8 / 256);
        f32_to_bf16_kernel<<<nb, 256, 0, stream>>>(Wx, Wxb, nw);
        f32_to_bf16_kernel<<<nb, 256, 0, stream>>>(Wh, Whb, nw);
    }

    for (int t0 = 0; t0 < T_DIM; t0 += (int)Tc) {
        int tc = (int)((T_DIM - t0 < Tc) ? (long)(T_DIM - t0) : Tc);

        long nx = (long)tc * B_DIM * D_DIM;
        f32_to_bf16_kernel<<<(int)(nx / 8 / 256), 256, 0, stream>>>(
            x + (long)t0 * B_DIM * D_DIM, xb, nx);

        dim3 gg(G_DIM / BN, (tc * B_DIM) / BM);
        gemm_xg_kernel<<<gg, 256, 0, stream>>>(xb, Wxb, bx, xg, tc * B_DIM);

        const __bf16* Whb_a = Whb;
        const float*  xg_a  = xg;
        const float*  mask_a = xmask;
        float*  cst_a = cst;
        __bf16* hb_a  = hb;
        float*  out_a = out;
        unsigned* fl_a = flags;
        int t0_a = t0, tc_a = tc;
        void* args[] = {(void*)&Whb_a, (void*)&xg_a, (void*)&mask_a,
                        (void*)&cst_a, (void*)&hb_a, (void*)&out_a,
                        (void*)&fl_a, (void*)&t0_a, (void*)&tc_a};
        hipLaunchCooperativeKernel((void*)lstm_scan_kernel, dim3(NWG), dim3(WGT),
                                   args, 0, stream);
    }
}

// Round 4
// 4052.332 us; speedup vs baseline: 2.0311x; 1.2650x over previous
//
#include <hip/hip_runtime.h>
#include <hip/hip_bf16.h>

using f32x4  = __attribute__((ext_vector_type(4))) float;
using bf16x8 = __attribute__((ext_vector_type(8))) __bf16;
using u64    = unsigned long long;

#define T_DIM 512
#define B_DIM 64
#define D_DIM 1024
#define H_DIM 1024
#define G_DIM 4096   // 4*H
#define NWG   128    // scan workgroups (wg owns 8 hidden units)
#define WGT   512    // threads per scan wg (8 waves)

// ---------------------------------------------------------------------------
// fp32 -> bf16 conversion (vectorized 8/thread)
// ---------------------------------------------------------------------------
__global__ void f32_to_bf16_kernel(const float* __restrict__ src,
                                   __bf16* __restrict__ dst, long n) {
    long i = ((long)blockIdx.x * blockDim.x + threadIdx.x) * 8;
    if (i + 8 <= n) {
        f32x4 a = *(const f32x4*)(src + i);
        f32x4 b = *(const f32x4*)(src + i + 4);
        bf16x8 o;
        o[0] = (__bf16)a[0]; o[1] = (__bf16)a[1];
        o[2] = (__bf16)a[2]; o[3] = (__bf16)a[3];
        o[4] = (__bf16)b[0]; o[5] = (__bf16)b[1];
        o[6] = (__bf16)b[2]; o[7] = (__bf16)b[3];
        *(bf16x8*)(dst + i) = o;
    }
}

// ---------------------------------------------------------------------------
// Phase 1: xg[M][4096] = A[M][1024](bf16) @ W[4096][1024]^T (bf16) + bias
// (unchanged — scan kernel is ~75% of runtime)
// ---------------------------------------------------------------------------
#define BM 128
#define BN 128
#define BK 64

__global__ __launch_bounds__(256) void gemm_xg_kernel(
    const __bf16* __restrict__ A,    // [M][1024]
    const __bf16* __restrict__ W,    // [4096][1024]
    const float* __restrict__ bias,  // [4096]
    float* __restrict__ C,           // [M][4096]
    int M)
{
    (void)M;
    __shared__ __bf16 sA[BM * BK];
    __shared__ __bf16 sB[BN * BK];

    const int tid = threadIdx.x;
    const int wv  = tid >> 6;
    const int l   = tid & 63;
    const int wy  = wv >> 1, wx = wv & 1;
    const int bm  = blockIdx.y * BM;
    const int bn  = blockIdx.x * BN;
    const int n   = l & 15;
    const int q   = l >> 4;

    const int srow  = l >> 3;
    const int skoff = (l & 7) * 8;

    f32x4 acc[4][4];
    #pragma unroll
    for (int mt = 0; mt < 4; ++mt)
        #pragma unroll
        for (int nt = 0; nt < 4; ++nt)
            acc[mt][nt] = (f32x4){0.f, 0.f, 0.f, 0.f};

    for (int kt = 0; kt < D_DIM / BK; ++kt) {
        const int k0 = kt * BK;
        #pragma unroll
        for (int j = 0; j < 4; ++j) {
            const int rbase = (j * 4 + wv) * 8;
            const __bf16* ga = A + (long)(bm + rbase + srow) * D_DIM + k0 + skoff;
            const __bf16* gb = W + (long)(bn + rbase + srow) * D_DIM + k0 + skoff;
            __builtin_amdgcn_global_load_lds(
                (const __attribute__((address_space(1))) void*)ga,
                (__attribute__((address_space(3))) void*)(sA + rbase * BK), 16, 0, 0);
            __builtin_amdgcn_global_load_lds(
                (const __attribute__((address_space(1))) void*)gb,
                (__attribute__((address_space(3))) void*)(sB + rbase * BK), 16, 0, 0);
        }
        __syncthreads();

        #pragma unroll
        for (int ks = 0; ks < 2; ++ks) {
            bf16x8 af[4], bfr[4];
            #pragma unroll
            for (int mt = 0; mt < 4; ++mt) {
                int row = wy * 64 + mt * 16 + n;
                af[mt] = *(const bf16x8*)(sA + row * BK + ks * 32 + q * 8);
            }
            #pragma unroll
            for (int nt = 0; nt < 4; ++nt) {
                int col = wx * 64 + nt * 16 + n;
                bfr[nt] = *(const bf16x8*)(sB + col * BK + ks * 32 + q * 8);
            }
            #pragma unroll
            for (int mt = 0; mt < 4; ++mt)
                #pragma unroll
                for (int nt = 0; nt < 4; ++nt)
                    acc[mt][nt] = __builtin_amdgcn_mfma_f32_16x16x32_bf16(
                        af[mt], bfr[nt], acc[mt][nt], 0, 0, 0);
        }
        __syncthreads();
    }

    #pragma unroll
    for (int nt = 0; nt < 4; ++nt) {
        int col = bn + wx * 64 + nt * 16 + n;
        float b = bias[col];
        #pragma unroll
        for (int mt = 0; mt < 4; ++mt) {
            #pragma unroll
            for (int r = 0; r < 4; ++r) {
                int row = bm + wy * 64 + mt * 16 + q * 4 + r;
                C[(long)row * G_DIM + col] = acc[mt][nt][r] + b;
            }
        }
    }
}

// ---------------------------------------------------------------------------
// fast tanh via __expf. err ~1e-6, tol 1.5e-2.
// ---------------------------------------------------------------------------
__device__ __forceinline__ float fast_tanh(float x) {
    return 1.0f - 2.0f / (__expf(2.0f * x) + 1.0f);
}

// ---------------------------------------------------------------------------
// Grid barrier, contention-free publish: per-wg flag padded to its own 64B
// line (128 plain agent-scope stores to 128 distinct MALL lines — no
// single-line RMW serialization as in round 3's counter). h stores (agent
// atomics, write-through) are drained by each wave's vmcnt(0) at the
// __syncthreads before the publish, so flag==target implies h(t+1) visible.
// Poll: wave 0, lane i covers flags[i] and flags[i+64], s_sleep backoff.
// ---------------------------------------------------------------------------
__device__ __forceinline__ void grid_barrier(unsigned* __restrict__ flags,
                                             unsigned target, int tid, int wgid) {
    __syncthreads();   // all waves: vmcnt(0) -> h stores visible at MALL
    if (tid == 0)
        __hip_atomic_store(&flags[wgid * 16], target, __ATOMIC_RELAXED,
                           __HIP_MEMORY_SCOPE_AGENT);
    if (tid < 64) {
        for (;;) {
            unsigned v0 = __hip_atomic_load(&flags[tid * 16],
                                            __ATOMIC_RELAXED, __HIP_MEMORY_SCOPE_AGENT);
            unsigned v1 = __hip_atomic_load(&flags[(tid + 64) * 16],
                                            __ATOMIC_RELAXED, __HIP_MEMORY_SCOPE_AGENT);
            if (__all((v0 >= target) & (v1 >= target))) break;
            __builtin_amdgcn_s_sleep(1);
        }
    }
    __syncthreads();
    __atomic_signal_fence(__ATOMIC_ACQUIRE);   // compiler-only: keep h loads after poll
}

// ---------------------------------------------------------------------------
// Phase 2: persistent scan. 128 wgs x 512 thr (8 waves); wg owns 8 hidden
// units (32 gate cols). M-SPLIT design (round-4): wave wv = (mb = wv>>1:
// 16-row M block, sub = wv&1: 16 of the 32 gate cols). Each wave computes its
// FINAL 16x16 gate tile over full K=1024:
//   - no cross-wave partial reduce (round 3's red[] phase + 2 barriers gone)
//   - breg = 32 bf16x8 = 128 VGPRs, resident (budget 256 at 1 wg/CU)
// h staged ONCE per step: all 128 KB in a single phase (wave wv stages rows
// 8wv..8wv+7 via 32 coalesced 512B agent loads), ONE exposed MALL RT,
// ONE __syncthreads, then 32 back-to-back MFMAs per wave (4 acc chains).
// ---------------------------------------------------------------------------
__global__ __launch_bounds__(WGT, 1) void lstm_scan_kernel(
    const __bf16* __restrict__ Whb,   // [4096][1024] bf16
    const float* __restrict__ xg,     // [tc][64][4096] fp32 (chunk-local)
    const float* __restrict__ mask,   // [512][64]
    float* __restrict__ cst,          // [64][1024] fp32 chunk-boundary state
    __bf16* __restrict__ hbuf,        // [2][64][1024] bf16 state
    float* __restrict__ out,          // [512][64][1024]
    unsigned* __restrict__ flags,     // [128] flags, 64B-padded
    int t0, int tc)
{
    __shared__ __align__(16) char shh[131072];  // full h(t): [64 rows][2048B], swizzled
    __shared__ float sg[8][16 * 17];            // per-wave gate exchange
    __shared__ float hp[8][64];                 // per-wave h pack

    const int tid  = threadIdx.x;
    const int wgid = blockIdx.x;
    const int wv   = tid >> 6;
    const int l    = tid & 63;
    const int n    = l & 15;
    const int q    = l >> 4;
    const int mb   = wv >> 1;        // M block (rows mb*16..mb*16+15)
    const int sub  = wv & 1;         // col half (units sub*4..sub*4+3 x 4 gates)

    // B col n -> gate n>>2, unit-in-sub n&3
    const int colg = ((n >> 2) << 10) + wgid * 8 + (sub << 2) + (n & 3);

    // Wh fragments, full K: 32 x bf16x8 = 128 VGPRs, loop-invariant
    bf16x8 breg[32];
    #pragma unroll
    for (int kk = 0; kk < 32; ++kk)
        breg[kk] = *(const bf16x8*)(Whb + (long)colg * H_DIM + kk * 32 + q * 8);

    // gate-phase ownership: (row, unit) per thread, within this wave's tile
    const int rloc = l >> 2;              // 0..15
    const int ui   = l & 3;               // 0..3
    const int grow = mb * 16 + rloc;      // batch row
    const int ucol = wgid * 8 + sub * 4 + ui;  // global hidden unit

    float c_r, h_r;
    if (t0 == 0) { c_r = 0.0f; h_r = 0.0f; }
    else {
        c_r = cst[grow * H_DIM + ucol];
        h_r = out[((long)(t0 - 1) * B_DIM + grow) * H_DIM + ucol];
    }

    // prefetch xg/mask for t = 0
    float xc0, xc1, xc2, xc3, mkc;
    {
        const float* xr = xg + (long)grow * G_DIM + ucol;
        xc0 = xr[0]; xc1 = xr[H_DIM]; xc2 = xr[2 * H_DIM]; xc3 = xr[3 * H_DIM];
        mkc = mask[t0 * B_DIM + grow];
    }

    const int arow  = mb * 16 + n;             // MFMA A row for this lane
    const char* abase_off = (const char*)0;    // (silence unused warnings pattern)
    (void)abase_off;
    const int swz_r = (n & 7) << 4;            // read-side XOR (arow&7 == n&7)

    for (int t = 0; t < tc; ++t) {
        const int gt = t0 + t;
        const __bf16* hread = hbuf + (long)(gt & 1) * (B_DIM * H_DIM);
        __bf16* hwrite = hbuf + (long)((gt + 1) & 1) * (B_DIM * H_DIM);
        const u64* h64 = (const u64*)hread;

        // ---- stage h(t): wave wv loads rows 8wv..8wv+7 (2KB each) in ONE
        // burst of 32 coalesced 512B wave-reads, then swizzled ds_writes ----
        u64 hold[32];
        #pragma unroll
        for (int j = 0; j < 8; ++j)
            #pragma unroll
            for (int c = 0; c < 4; ++c)
                hold[j * 4 + c] = __hip_atomic_load(
                    h64 + (long)(wv * 8 + j) * 256 + c * 64 + l,
                    __ATOMIC_RELAXED, __HIP_MEMORY_SCOPE_AGENT);
        #pragma unroll
        for (int j = 0; j < 8; ++j) {
            char* base = shh + (wv * 8 + j) * 2048;
            const int swz = (j & 7) << 4;      // (8wv+j)&7 == j
            #pragma unroll
            for (int c = 0; c < 4; ++c)
                *(u64*)(base + ((c * 512 + l * 8) ^ swz)) = hold[j * 4 + c];
        }
        __syncthreads();

        // ---- 32 MFMAs, full K, 4 independent acc chains ----
        f32x4 a0 = {0.f,0.f,0.f,0.f}, a1 = {0.f,0.f,0.f,0.f};
        f32x4 a2 = {0.f,0.f,0.f,0.f}, a3 = {0.f,0.f,0.f,0.f};
        const char* abase = shh + arow * 2048;
        #pragma unroll
        for (int kk = 0; kk < 32; kk += 4) {
            bf16x8 f0 = *(const bf16x8*)(abase + (((kk + 0) * 64 + q * 16) ^ swz_r));
            bf16x8 f1 = *(const bf16x8*)(abase + (((kk + 1) * 64 + q * 16) ^ swz_r));
            bf16x8 f2 = *(const bf16x8*)(abase + (((kk + 2) * 64 + q * 16) ^ swz_r));
            bf16x8 f3 = *(const bf16x8*)(abase + (((kk + 3) * 64 + q * 16) ^ swz_r));
            a0 = __builtin_amdgcn_mfma_f32_16x16x32_bf16(f0, breg[kk + 0], a0, 0, 0, 0);
            a1 = __builtin_amdgcn_mfma_f32_16x16x32_bf16(f1, breg[kk + 1], a1, 0, 0, 0);
            a2 = __builtin_amdgcn_mfma_f32_16x16x32_bf16(f2, breg[kk + 2], a2, 0, 0, 0);
            a3 = __builtin_amdgcn_mfma_f32_16x16x32_bf16(f3, breg[kk + 3], a3, 0, 0, 0);
        }
        f32x4 acc = (a0 + a1) + (a2 + a3);

        // ---- gate exchange via per-wave LDS (same-wave write->read) ----
        #pragma unroll
        for (int r = 0; r < 4; ++r)
            sg[wv][(q * 4 + r) * 17 + n] = acc[r];

        float ig = xc0 + sg[wv][rloc * 17 + 0  + ui];
        float fg = xc1 + sg[wv][rloc * 17 + 4  + ui];
        float og = xc2 + sg[wv][rloc * 17 + 8  + ui];
        float gg = xc3 + sg[wv][rloc * 17 + 12 + ui];

        float i_s = 1.0f / (1.0f + __expf(-ig));
        float f_s = 1.0f / (1.0f + __expf(-fg));
        float o_s = 1.0f / (1.0f + __expf(-og));
        float g_t = fast_tanh(gg);
        float c_new = f_s * c_r + i_s * g_t;
        float h_new = o_s * fast_tanh(c_new);
        float c_f = mkc * c_new + (1.0f - mkc) * c_r;
        float h_f = mkc * h_new + (1.0f - mkc) * h_r;
        c_r = c_f;
        h_r = h_f;

        // ---- packed h store: 4 units/row -> one 8B agent store ----
        hp[wv][l] = h_f;                       // l == rloc*4 + ui: [row][unit]
        if (l < 16) {
            float v0 = hp[wv][l * 4 + 0];
            float v1 = hp[wv][l * 4 + 1];
            float v2 = hp[wv][l * 4 + 2];
            float v3 = hp[wv][l * 4 + 3];
            unsigned short b0 = __builtin_bit_cast(unsigned short, (__bf16)v0);
            unsigned short b1 = __builtin_bit_cast(unsigned short, (__bf16)v1);
            unsigned short b2 = __builtin_bit_cast(unsigned short, (__bf16)v2);
            unsigned short b3 = __builtin_bit_cast(unsigned short, (__bf16)v3);
            u64 pk = (u64)b0 | ((u64)b1 << 16) | ((u64)b2 << 32) | ((u64)b3 << 48);
            u64* dp = (u64*)((unsigned short*)hwrite +
                             (long)(mb * 16 + l) * H_DIM + wgid * 8 + sub * 4);
            __hip_atomic_store(dp, pk, __ATOMIC_RELAXED, __HIP_MEMORY_SCOPE_AGENT);
        }

        out[((long)gt * B_DIM + grow) * H_DIM + ucol] = h_f;
        if (t == tc - 1) cst[grow * H_DIM + ucol] = c_f;

        // prefetch next step's xg/mask (issued before the barrier -> hidden)
        if (t + 1 < tc) {
            const float* xr = xg + ((long)(t + 1) * B_DIM + grow) * G_DIM + ucol;
            xc0 = xr[0]; xc1 = xr[H_DIM]; xc2 = xr[2 * H_DIM]; xc3 = xr[3 * H_DIM];
            mkc = mask[(gt + 1) * B_DIM + grow];
        }

        grid_barrier(flags, (unsigned)(gt + 1), tid, wgid);
    }
}

// ---------------------------------------------------------------------------
// Host side. Workspace:
//   [Whb 8MiB][Wxb 8MiB][hbuf 2x128KiB][cst 256KiB][flags 8KiB pad-64B]
//   (pad to 1MiB) [xb chunk][xg chunk]
// ---------------------------------------------------------------------------
extern "C" void kernel_launch(void* const* d_in, const int* in_sizes, int n_in,
                              void* d_out, int out_size, void* d_ws, size_t ws_size,
                              hipStream_t stream)
{
    (void)in_sizes; (void)n_in; (void)out_size;
    const float* x     = (const float*)d_in[0];  // [512][64][1024]
    const float* xmask = (const float*)d_in[1];  // [512][64]
    const float* Wx    = (const float*)d_in[2];  // [4096][1024]
    const float* bx    = (const float*)d_in[3];  // [4096]
    const float* Wh    = (const float*)d_in[4];  // [4096][1024]
    float* out = (float*)d_out;

    char* ws = (char*)d_ws;
    __bf16*   Whb   = (__bf16*)(ws);
    __bf16*   Wxb   = (__bf16*)(ws + 8388608);
    __bf16*   hb    = (__bf16*)(ws + 16777216);             // 2 x 131072 B
    float*    cst   = (float*)(ws + 16777216 + 262144);     // 262144 B
    unsigned* flags = (unsigned*)(ws + 16777216 + 524288);  // 8192 B (64B-padded)
    char* dyn = ws + 16777216 + 1048576;

    long avail = (long)ws_size - (16777216L + 1048576L);
    const long per_t = (long)B_DIM * D_DIM * 2 + (long)B_DIM * G_DIM * 4;
    long Tc = avail > 0 ? avail / per_t : 2;
    if (Tc > T_DIM) Tc = T_DIM;
    Tc &= ~1L;
    if (Tc < 2) Tc = 2;

    __bf16* xb = (__bf16*)dyn;
    float*  xg = (float*)(dyn + Tc * (long)B_DIM * D_DIM * 2);

    // zero h0 state + barrier flags
    hipMemsetAsync(ws + 16777216, 0, 1048576, stream);

    {
        long nw = (long)G_DIM * D_DIM;
        int nb = (int)(nw / 8 / 256);
        f32_to_bf16_kernel<<<nb, 256, 0, stream>>>(Wx, Wxb, nw);
        f32_to_bf16_kernel<<<nb, 256, 0, stream>>>(Wh, Whb, nw);
    }

    for (int t0 = 0; t0 < T_DIM; t0 += (int)Tc) {
        int tc = (int)((T_DIM - t0 < Tc) ? (long)(T_DIM - t0) : Tc);

        long nx = (long)tc * B_DIM * D_DIM;
        f32_to_bf16_kernel<<<(int)(nx / 8 / 256), 256, 0, stream>>>(
            x + (long)t0 * B_DIM * D_DIM, xb, nx);

        dim3 gg(G_DIM / BN, (tc * B_DIM) / BM);
        gemm_xg_kernel<<<gg, 256, 0, stream>>>(xb, Wxb, bx, xg, tc * B_DIM);

        const __bf16* Whb_a = Whb;
        const float*  xg_a  = xg;
        const float*  mask_a = xmask;
        float*  cst_a = cst;
        __bf16* hb_a  = hb;
        float*  out_a = out;
        unsigned* fl_a = flags;
        int t0_a = t0, tc_a = tc;
        void* args[] = {(void*)&Whb_a, (void*)&xg_a, (void*)&mask_a,
                        (void*)&cst_a, (void*)&hb_a, (void*)&out_a,
                        (void*)&fl_a, (void*)&t0_a, (void*)&tc_a};
        hipLaunchCooperativeKernel((void*)lstm_scan_kernel, dim3(NWG), dim3(WGT),
                                   args, 0, stream);
    }
}

// Round 5
// 2531.573 us; speedup vs baseline: 3.2513x; 1.6007x over previous
//
#include <hip/hip_runtime.h>
#include <hip/hip_bf16.h>

using f32x4  = __attribute__((ext_vector_type(4))) float;
using bf16x8 = __attribute__((ext_vector_type(8))) __bf16;
using u64    = unsigned long long;

#define T_DIM 512
#define B_DIM 64
#define D_DIM 1024
#define H_DIM 1024
#define G_DIM 4096   // 4*H
#define NWG   128    // scan wgs: 4 row-blocks x 32 unit-blocks
#define WGT   512    // threads per scan wg (8 waves)

// ---------------------------------------------------------------------------
// fp32 -> bf16 conversion (vectorized 8/thread)
// ---------------------------------------------------------------------------
__global__ void f32_to_bf16_kernel(const float* __restrict__ src,
                                   __bf16* __restrict__ dst, long n) {
    long i = ((long)blockIdx.x * blockDim.x + threadIdx.x) * 8;
    if (i + 8 <= n) {
        f32x4 a = *(const f32x4*)(src + i);
        f32x4 b = *(const f32x4*)(src + i + 4);
        bf16x8 o;
        o[0] = (__bf16)a[0]; o[1] = (__bf16)a[1];
        o[2] = (__bf16)a[2]; o[3] = (__bf16)a[3];
        o[4] = (__bf16)b[0]; o[5] = (__bf16)b[1];
        o[6] = (__bf16)b[2]; o[7] = (__bf16)b[3];
        *(bf16x8*)(dst + i) = o;
    }
}

// ---------------------------------------------------------------------------
// Phase 1: xg[M][4096] = A[M][1024](bf16) @ W[4096][1024]^T (bf16) + bias
// (unchanged — scan kernel is ~71% of runtime)
// ---------------------------------------------------------------------------
#define BM 128
#define BN 128
#define BK 64

__global__ __launch_bounds__(256) void gemm_xg_kernel(
    const __bf16* __restrict__ A,    // [M][1024]
    const __bf16* __restrict__ W,    // [4096][1024]
    const float* __restrict__ bias,  // [4096]
    float* __restrict__ C,           // [M][4096]
    int M)
{
    (void)M;
    __shared__ __bf16 sA[BM * BK];
    __shared__ __bf16 sB[BN * BK];

    const int tid = threadIdx.x;
    const int wv  = tid >> 6;
    const int l   = tid & 63;
    const int wy  = wv >> 1, wx = wv & 1;
    const int bm  = blockIdx.y * BM;
    const int bn  = blockIdx.x * BN;
    const int n   = l & 15;
    const int q   = l >> 4;

    const int srow  = l >> 3;
    const int skoff = (l & 7) * 8;

    f32x4 acc[4][4];
    #pragma unroll
    for (int mt = 0; mt < 4; ++mt)
        #pragma unroll
        for (int nt = 0; nt < 4; ++nt)
            acc[mt][nt] = (f32x4){0.f, 0.f, 0.f, 0.f};

    for (int kt = 0; kt < D_DIM / BK; ++kt) {
        const int k0 = kt * BK;
        #pragma unroll
        for (int j = 0; j < 4; ++j) {
            const int rbase = (j * 4 + wv) * 8;
            const __bf16* ga = A + (long)(bm + rbase + srow) * D_DIM + k0 + skoff;
            const __bf16* gb = W + (long)(bn + rbase + srow) * D_DIM + k0 + skoff;
            __builtin_amdgcn_global_load_lds(
                (const __attribute__((address_space(1))) void*)ga,
                (__attribute__((address_space(3))) void*)(sA + rbase * BK), 16, 0, 0);
            __builtin_amdgcn_global_load_lds(
                (const __attribute__((address_space(1))) void*)gb,
                (__attribute__((address_space(3))) void*)(sB + rbase * BK), 16, 0, 0);
        }
        __syncthreads();

        #pragma unroll
        for (int ks = 0; ks < 2; ++ks) {
            bf16x8 af[4], bfr[4];
            #pragma unroll
            for (int mt = 0; mt < 4; ++mt) {
                int row = wy * 64 + mt * 16 + n;
                af[mt] = *(const bf16x8*)(sA + row * BK + ks * 32 + q * 8);
            }
            #pragma unroll
            for (int nt = 0; nt < 4; ++nt) {
                int col = wx * 64 + nt * 16 + n;
                bfr[nt] = *(const bf16x8*)(sB + col * BK + ks * 32 + q * 8);
            }
            #pragma unroll
            for (int mt = 0; mt < 4; ++mt)
                #pragma unroll
                for (int nt = 0; nt < 4; ++nt)
                    acc[mt][nt] = __builtin_amdgcn_mfma_f32_16x16x32_bf16(
                        af[mt], bfr[nt], acc[mt][nt], 0, 0, 0);
        }
        __syncthreads();
    }

    #pragma unroll
    for (int nt = 0; nt < 4; ++nt) {
        int col = bn + wx * 64 + nt * 16 + n;
        float b = bias[col];
        #pragma unroll
        for (int mt = 0; mt < 4; ++mt) {
            #pragma unroll
            for (int r = 0; r < 4; ++r) {
                int row = bm + wy * 64 + mt * 16 + q * 4 + r;
                C[(long)row * G_DIM + col] = acc[mt][nt][r] + b;
            }
        }
    }
}

// ---------------------------------------------------------------------------
// fast tanh via __expf. err ~1e-6, tol 1.5e-2.
// ---------------------------------------------------------------------------
__device__ __forceinline__ float fast_tanh(float x) {
    return 1.0f - 2.0f / (__expf(2.0f * x) + 1.0f);
}

// ---------------------------------------------------------------------------
// Grid barrier (round-4 proven): per-wg flag on its own 64B line, plain
// agent-scope stores, wave-0 poll with s_sleep backoff. h stores (agent
// atomics, write-through) are drained by each wave's vmcnt(0) at the
// __syncthreads before the publish, so flag==target implies h(t+1) visible.
// ---------------------------------------------------------------------------
__device__ __forceinline__ void grid_barrier(unsigned* __restrict__ flags,
                                             unsigned target, int tid, int wgid) {
    __syncthreads();   // all waves: vmcnt(0) -> h stores visible at MALL
    if (tid == 0)
        __hip_atomic_store(&flags[wgid * 16], target, __ATOMIC_RELAXED,
                           __HIP_MEMORY_SCOPE_AGENT);
    if (tid < 64) {
        for (;;) {
            unsigned v0 = __hip_atomic_load(&flags[tid * 16],
                                            __ATOMIC_RELAXED, __HIP_MEMORY_SCOPE_AGENT);
            unsigned v1 = __hip_atomic_load(&flags[(tid + 64) * 16],
                                            __ATOMIC_RELAXED, __HIP_MEMORY_SCOPE_AGENT);
            if (__all((v0 >= target) & (v1 >= target))) break;
            __builtin_amdgcn_s_sleep(1);
        }
    }
    __syncthreads();
    __atomic_signal_fence(__ATOMIC_ACQUIRE);   // compiler-only: keep h loads after poll
}

// ---------------------------------------------------------------------------
// Phase 2: persistent scan, ROW x UNIT partition (round 5).
// 128 wgs x 512 thr. wg = (rblk = wgid>>5: rows rblk*16..+15,
//                          ublk = wgid&31: units ublk*32..+31).
// 8 waves hold DISJOINT Wh slices: wave w -> gate gw=w>>1, col-half w&1;
// 16 gate-cols x full K=1024 = 32 bf16x8 = 128 VGPRs, loop-invariant.
//   - wg h-read: only its 16 rows = 32 KB/step (grid total 4 MB/step,
//     4x less than round 4)
//   - stage burst: 8 u64/lane (16 VGPRs) -> no register-pressure
//     serialization, ONE exposed MALL RT
//   - LDS in FRAGMENT-MAJOR layout (kk*1024 + q*256 + row*16): every
//     ds_read_b128 is 1024B contiguous -> bank-floor, no conflicts
// amdgpu_waves_per_eu(2,2): exactly 2 waves/SIMD -> 256-VGPR budget, stops
// the allocator from squeezing to 128 and re-loading Wh (rounds 2-4 bug).
// ---------------------------------------------------------------------------
__global__ __launch_bounds__(WGT)
__attribute__((amdgpu_waves_per_eu(2, 2)))
void lstm_scan_kernel(
    const __bf16* __restrict__ Whb,   // [4096][1024] bf16
    const float* __restrict__ xg,     // [tc][64][4096] fp32 (chunk-local)
    const float* __restrict__ mask,   // [512][64]
    float* __restrict__ cst,          // [64][1024] fp32 chunk-boundary state
    __bf16* __restrict__ hbuf,        // [2][64][1024] bf16 state
    float* __restrict__ out,          // [512][64][1024]
    unsigned* __restrict__ flags,     // [128] flags, 64B-padded
    int t0, int tc)
{
    __shared__ __align__(16) char shh[32768];       // h rows, fragment-major
    __shared__ float sg[16][132];                   // gate tile [row][4*32 cols]
    __shared__ unsigned short hp[16][32];           // h pack [row][unit]

    const int tid  = threadIdx.x;
    const int wgid = blockIdx.x;
    const int rblk = wgid >> 5;          // row block 0..3
    const int ublk = wgid & 31;          // unit block 0..31
    const int wv   = tid >> 6;
    const int l    = tid & 63;
    const int n    = l & 15;
    const int q    = l >> 4;
    const int gw   = wv >> 1;            // gate 0..3
    const int ch   = wv & 1;             // col half 0..1

    // this wave's 16 gate columns: gate gw, units ublk*32 + ch*16 + n
    const int colg = gw * H_DIM + ublk * 32 + ch * 16 + n;

    // Wh fragments, full K: 32 x bf16x8 = 128 VGPRs, loop-invariant
    bf16x8 breg[32];
    #pragma unroll
    for (int kk = 0; kk < 32; ++kk)
        breg[kk] = *(const bf16x8*)(Whb + (long)colg * H_DIM + kk * 32 + q * 8);

    // gate-phase ownership: (row, unit) per thread
    const int grow_l = tid >> 5;               // 0..15
    const int u      = tid & 31;               // 0..31
    const int grow   = rblk * 16 + grow_l;     // global batch row
    const int ucol   = ublk * 32 + u;          // global hidden unit

    float c_r, h_r;
    if (t0 == 0) { c_r = 0.0f; h_r = 0.0f; }
    else {
        c_r = cst[grow * H_DIM + ucol];
        h_r = out[((long)(t0 - 1) * B_DIM + grow) * H_DIM + ucol];
    }

    // prefetch xg/mask for t = 0
    float xc0, xc1, xc2, xc3, mkc;
    {
        const float* xr = xg + (long)grow * G_DIM + ucol;
        xc0 = xr[0]; xc1 = xr[H_DIM]; xc2 = xr[2 * H_DIM]; xc3 = xr[3 * H_DIM];
        mkc = mask[t0 * B_DIM + grow];
    }

    // staging geometry: wave wv handles kk = wv*4 .. wv*4+3; per (kk, rh):
    // lane l loads u64 of h row rblk*16+rh+(l>>3), row-bytes [kk*64+(l&7)*8, +8)
    const int srow_lo = (l >> 3);        // 0..7
    const int sv      = l & 7;           // byte-in-64 selector
    const int sq      = (l >> 1) & 3;    // fragment q of this u64
    const int sb      = (l & 1) * 8;     // byte-in-fragment

    for (int t = 0; t < tc; ++t) {
        const int gt = t0 + t;
        const __bf16* hread = hbuf + (long)(gt & 1) * (B_DIM * H_DIM);
        __bf16* hwrite = hbuf + (long)((gt + 1) & 1) * (B_DIM * H_DIM);
        const u64* h64 = (const u64*)hread;

        // ---- stage: 8 coherent loads (one burst, 16 VGPRs of holds) ----
        u64 hold[8];
        #pragma unroll
        for (int j = 0; j < 4; ++j) {
            const int kk = wv * 4 + j;
            hold[j * 2]     = __hip_atomic_load(
                h64 + (long)(rblk * 16 + srow_lo) * 256 + kk * 8 + sv,
                __ATOMIC_RELAXED, __HIP_MEMORY_SCOPE_AGENT);
            hold[j * 2 + 1] = __hip_atomic_load(
                h64 + (long)(rblk * 16 + 8 + srow_lo) * 256 + kk * 8 + sv,
                __ATOMIC_RELAXED, __HIP_MEMORY_SCOPE_AGENT);
        }
        // fragment-major LDS writes (<=4-way bank alias, cheap)
        #pragma unroll
        for (int j = 0; j < 4; ++j) {
            const int kk = wv * 4 + j;
            *(u64*)(shh + kk * 1024 + sq * 256 + srow_lo * 16 + sb)       = hold[j * 2];
            *(u64*)(shh + kk * 1024 + sq * 256 + (8 + srow_lo) * 16 + sb) = hold[j * 2 + 1];
        }
        __syncthreads();

        // ---- 32 MFMAs, full K, contiguous 1KB ds_read_b128 per step ----
        f32x4 ac0 = {0.f,0.f,0.f,0.f}, ac1 = {0.f,0.f,0.f,0.f};
        #pragma unroll
        for (int kk = 0; kk < 32; kk += 2) {
            bf16x8 f0 = *(const bf16x8*)(shh + (kk + 0) * 1024 + q * 256 + n * 16);
            bf16x8 f1 = *(const bf16x8*)(shh + (kk + 1) * 1024 + q * 256 + n * 16);
            ac0 = __builtin_amdgcn_mfma_f32_16x16x32_bf16(f0, breg[kk + 0], ac0, 0, 0, 0);
            ac1 = __builtin_amdgcn_mfma_f32_16x16x32_bf16(f1, breg[kk + 1], ac1, 0, 0, 0);
        }
        f32x4 acc = ac0 + ac1;

        // ---- cross-wave gate exchange: sg[row][gate*32 + unit] ----
        {
            const int cw = gw * 32 + ch * 16 + n;
            #pragma unroll
            for (int r = 0; r < 4; ++r)
                sg[q * 4 + r][cw] = acc[r];
        }
        __syncthreads();

        float ig = xc0 + sg[grow_l][u];
        float fg = xc1 + sg[grow_l][32 + u];
        float og = xc2 + sg[grow_l][64 + u];
        float gg = xc3 + sg[grow_l][96 + u];

        float i_s = 1.0f / (1.0f + __expf(-ig));
        float f_s = 1.0f / (1.0f + __expf(-fg));
        float o_s = 1.0f / (1.0f + __expf(-og));
        float g_t = fast_tanh(gg);
        float c_new = f_s * c_r + i_s * g_t;
        float h_new = o_s * fast_tanh(c_new);
        float c_f = mkc * c_new + (1.0f - mkc) * c_r;
        float h_f = mkc * h_new + (1.0f - mkc) * h_r;
        c_r = c_f;
        h_r = h_f;

        // ---- pack h (bf16) in LDS, store as 8B agent-scope chunks ----
        hp[grow_l][u] = __builtin_bit_cast(unsigned short, (__bf16)h_f);
        __syncthreads();
        if (tid < 128) {
            const int prow = tid >> 3, pseg = tid & 7;
            u64 pk = *(const u64*)(&hp[prow][pseg * 4]);
            u64* dp = (u64*)((unsigned short*)hwrite +
                             (long)(rblk * 16 + prow) * H_DIM + ublk * 32 + pseg * 4);
            __hip_atomic_store(dp, pk, __ATOMIC_RELAXED, __HIP_MEMORY_SCOPE_AGENT);
        }

        out[((long)gt * B_DIM + grow) * H_DIM + ucol] = h_f;
        if (t == tc - 1) cst[grow * H_DIM + ucol] = c_f;

        // prefetch next step's xg/mask (issued before the barrier -> hidden)
        if (t + 1 < tc) {
            const float* xr = xg + ((long)(t + 1) * B_DIM + grow) * G_DIM + ucol;
            xc0 = xr[0]; xc1 = xr[H_DIM]; xc2 = xr[2 * H_DIM]; xc3 = xr[3 * H_DIM];
            mkc = mask[(gt + 1) * B_DIM + grow];
        }

        grid_barrier(flags, (unsigned)(gt + 1), tid, wgid);
    }
}

// ---------------------------------------------------------------------------
// Host side. Workspace:
//   [Whb 8MiB][Wxb 8MiB][hbuf 2x128KiB][cst 256KiB][flags 8KiB pad-64B]
//   (pad to 1MiB) [xb chunk][xg chunk]
// ---------------------------------------------------------------------------
extern "C" void kernel_launch(void* const* d_in, const int* in_sizes, int n_in,
                              void* d_out, int out_size, void* d_ws, size_t ws_size,
                              hipStream_t stream)
{
    (void)in_sizes; (void)n_in; (void)out_size;
    const float* x     = (const float*)d_in[0];  // [512][64][1024]
    const float* xmask = (const float*)d_in[1];  // [512][64]
    const float* Wx    = (const float*)d_in[2];  // [4096][1024]
    const float* bx    = (const float*)d_in[3];  // [4096]
    const float* Wh    = (const float*)d_in[4];  // [4096][1024]
    float* out = (float*)d_out;

    char* ws = (char*)d_ws;
    __bf16*   Whb   = (__bf16*)(ws);
    __bf16*   Wxb   = (__bf16*)(ws + 8388608);
    __bf16*   hb    = (__bf16*)(ws + 16777216);             // 2 x 131072 B
    float*    cst   = (float*)(ws + 16777216 + 262144);     // 262144 B
    unsigned* flags = (unsigned*)(ws + 16777216 + 524288);  // 8192 B (64B-padded)
    char* dyn = ws + 16777216 + 1048576;

    long avail = (long)ws_size - (16777216L + 1048576L);
    const long per_t = (long)B_DIM * D_DIM * 2 + (long)B_DIM * G_DIM * 4;
    long Tc = avail > 0 ? avail / per_t : 2;
    if (Tc > T_DIM) Tc = T_DIM;
    Tc &= ~1L;
    if (Tc < 2) Tc = 2;

    __bf16* xb = (__bf16*)dyn;
    float*  xg = (float*)(dyn + Tc * (long)B_DIM * D_DIM * 2);

    // zero h0 state + barrier flags
    hipMemsetAsync(ws + 16777216, 0, 1048576, stream);

    {
        long nw = (long)G_DIM * D_DIM;
        int nb = (int)(nw / 8 / 256);
        f32_to_bf16_kernel<<<nb, 256, 0, stream>>>(Wx, Wxb, nw);
        f32_to_bf16_kernel<<<nb, 256, 0, stream>>>(Wh, Whb, nw);
    }

    for (int t0 = 0; t0 < T_DIM; t0 += (int)Tc) {
        int tc = (int)((T_DIM - t0 < Tc) ? (long)(T_DIM - t0) : Tc);

        long nx = (long)tc * B_DIM * D_DIM;
        f32_to_bf16_kernel<<<(int)(nx / 8 / 256), 256, 0, stream>>>(
            x + (long)t0 * B_DIM * D_DIM, xb, nx);

        dim3 gg(G_DIM / BN, (tc * B_DIM) / BM);
        gemm_xg_kernel<<<gg, 256, 0, stream>>>(xb, Wxb, bx, xg, tc * B_DIM);

        const __bf16* Whb_a = Whb;
        const float*  xg_a  = xg;
        const float*  mask_a = xmask;
        float*  cst_a = cst;
        __bf16* hb_a  = hb;
        float*  out_a = out;
        unsigned* fl_a = flags;
        int t0_a = t0, tc_a = tc;
        void* args[] = {(void*)&Whb_a, (void*)&xg_a, (void*)&mask_a,
                        (void*)&cst_a, (void*)&hb_a, (void*)&out_a,
                        (void*)&fl_a, (void*)&t0_a, (void*)&tc_a};
        hipLaunchCooperativeKernel((void*)lstm_scan_kernel, dim3(NWG), dim3(WGT),
                                   args, 0, stream);
    }
}